// Round 5
// baseline (532.855 us; speedup 1.0000x reference)
//
#include <hip/hip_runtime.h>
#include <cmath>

#define T_SEQ 2048
#define WINDOW 1024

typedef __attribute__((ext_vector_type(8))) short bf16x8;
typedef __attribute__((ext_vector_type(4))) float f32x4;
typedef __attribute__((ext_vector_type(16))) float f32x16;

__device__ __forceinline__ unsigned short f2bf(float f) {
  union { float f; unsigned int u; } v; v.f = f;
  unsigned int r = v.u + 0x7FFFu + ((v.u >> 16) & 1u);  // RNE
  return (unsigned short)(r >> 16);
}
__device__ __forceinline__ float bf2f(unsigned short u) {
  union { unsigned int i; float f; } v; v.i = ((unsigned int)u) << 16;
  return v.f;
}

#define GLD16(gp, lp)                                                  \
  __builtin_amdgcn_global_load_lds(                                    \
      (__attribute__((address_space(1))) unsigned int*)(gp),           \
      (__attribute__((address_space(3))) unsigned int*)(lp), 16, 0, 0)

// ---------------------------------------------------------------------------
// prep: fused cast_bf16(x) + transpose_wqkv + transpose_wo.
// ---------------------------------------------------------------------------
__global__ __launch_bounds__(256) void prep(
    const float* __restrict__ x,
    const float* __restrict__ qw, const float* __restrict__ kw,
    const float* __restrict__ vw, const float* __restrict__ ow,
    unsigned short* __restrict__ xb, unsigned short* __restrict__ wqkvt,
    unsigned short* __restrict__ wot) {
  __shared__ float tile[64][65];
  const int blk = blockIdx.x;
  const int tid = threadIdx.x;
  if (blk < 8192) {
    size_t i = (size_t)blk * 256 + tid;
    float4 v = *(const float4*)&x[i * 4];
    ushort4 o;
    o.x = f2bf(v.x); o.y = f2bf(v.y); o.z = f2bf(v.z); o.w = f2bf(v.w);
    *(ushort4*)&xb[i * 4] = o;
    return;
  }
  int tx = tid & 15, ty = tid >> 4;
  if (blk < 10240) {
    int idx = blk - 8192;
    int c0 = (idx & 63) * 64, d0 = (idx >> 6) * 64;
    const float* src; int hbase;
    if (c0 < 2048) { src = qw + (size_t)(c0 >> 8) * 524288; hbase = c0 & 255; }
    else if (c0 < 3072) { int cc = c0 - 2048; src = kw + (size_t)(cc >> 8) * 524288; hbase = cc & 255; }
    else { int cc = c0 - 3072; src = vw + (size_t)(cc >> 8) * 524288; hbase = cc & 255; }
#pragma unroll
    for (int p = 0; p < 4; ++p) {
      float4 v = *(const float4*)&src[(size_t)(d0 + ty + 16 * p) * 256 + hbase + tx * 4];
      tile[ty + 16 * p][tx * 4 + 0] = v.x; tile[ty + 16 * p][tx * 4 + 1] = v.y;
      tile[ty + 16 * p][tx * 4 + 2] = v.z; tile[ty + 16 * p][tx * 4 + 3] = v.w;
    }
    __syncthreads();
#pragma unroll
    for (int p = 0; p < 4; ++p) {
      int hh = ty + 16 * p;
      ushort4 o;
      o.x = f2bf(tile[tx * 4 + 0][hh]); o.y = f2bf(tile[tx * 4 + 1][hh]);
      o.z = f2bf(tile[tx * 4 + 2][hh]); o.w = f2bf(tile[tx * 4 + 3][hh]);
      *(ushort4*)&wqkvt[(size_t)(c0 + hh) * 2048 + d0 + tx * 4] = o;
    }
  } else {
    int idx = blk - 10240;
    int j0 = (idx & 31) * 64, d0 = (idx >> 5) * 64;
#pragma unroll
    for (int p = 0; p < 4; ++p) {
      float4 v = *(const float4*)&ow[(size_t)(j0 + ty + 16 * p) * 2048 + d0 + tx * 4];
      tile[ty + 16 * p][tx * 4 + 0] = v.x; tile[ty + 16 * p][tx * 4 + 1] = v.y;
      tile[ty + 16 * p][tx * 4 + 2] = v.z; tile[ty + 16 * p][tx * 4 + 3] = v.w;
    }
    __syncthreads();
#pragma unroll
    for (int p = 0; p < 4; ++p) {
      int hh = ty + 16 * p;
      ushort4 o;
      o.x = f2bf(tile[tx * 4 + 0][hh]); o.y = f2bf(tile[tx * 4 + 1][hh]);
      o.z = f2bf(tile[tx * 4 + 2][hh]); o.w = f2bf(tile[tx * 4 + 3][hh]);
      *(ushort4*)&wot[(size_t)(d0 + hh) * 2048 + j0 + tx * 4] = o;
    }
  }
}

// ---------------------------------------------------------------------------
// 256x256-tile 8-phase bf16 MFMA GEMM for the QKV projection (T1+T2+T3+T4+T5).
// ---------------------------------------------------------------------------
__global__ __launch_bounds__(512) void gemm_qkv_256(
    const unsigned short* __restrict__ xb, const unsigned short* __restrict__ wt,
    unsigned short* __restrict__ qo, unsigned short* __restrict__ ko,
    unsigned short* __restrict__ vo) {
  __shared__ unsigned short lds[65536];  // 128 KB
  const int tid = threadIdx.x;
  const int wave = tid >> 6, lane = tid & 63;
  const int wr = wave >> 2, wc = wave & 3;
  const int fm = lane & 15, fk = lane >> 4;

  const int bid = blockIdx.x;
  const int swz = (bid & 7) * 32 + (bid >> 3);
  const int m0 = (swz >> 4) * 256, n0 = (swz & 15) * 256;

  const int soff = fm * 32 + ((fk ^ ((fm >> 2) & 3)) << 3);
  const int aoff = wr * 4096 + soff;  // + i*512
  const int boff = wc * 2048 + soff;  // + j*512

  const unsigned short* Ab = xb + (size_t)m0 * 2048;
  const unsigned short* Bb = wt + (size_t)n0 * 2048;

  const int l0 = tid, l1 = tid + 512;
  const int r0 = l0 >> 2, o0 = l0 & 3;
  const int r1 = l1 >> 2, o1 = l1 & 3;
  const int sA0 = r0 * 2048 + ((o0 ^ ((r0 >> 2) & 3)) << 3);
  const int sA1 = r1 * 2048 + ((o1 ^ ((r1 >> 2) & 3)) << 3);

#define STAGE(srcbase, kofs, dstbase)                  \
  do {                                                 \
    GLD16((srcbase) + sA0 + (kofs), (dstbase) + l0 * 8); \
    GLD16((srcbase) + sA1 + (kofs), (dstbase) + l1 * 8); \
  } while (0)

  f32x4 acc[8][4];
#pragma unroll
  for (int i = 0; i < 8; ++i)
#pragma unroll
    for (int j = 0; j < 4; ++j) acc[i][j] = {0.f, 0.f, 0.f, 0.f};

  STAGE(Ab, 0,  lds + 0);
  STAGE(Bb, 0,  lds + 16384);
  STAGE(Ab, 32, lds + 8192);
  STAGE(Bb, 32, lds + 24576);
  STAGE(Ab, 64, lds + 32768);
  STAGE(Bb, 64, lds + 49152);
  asm volatile("s_waitcnt vmcnt(8)" ::: "memory");
  __builtin_amdgcn_s_barrier();

  for (int t = 0; t < 32; ++t) {
    const int p = t & 1;
    unsigned short* base = lds + p * 32768;
    unsigned short* xbase = lds + (p ^ 1) * 32768;
    const int t1 = (t < 31) ? t + 1 : 31;
    const int t2 = (t < 30) ? t + 2 : 31;

    bf16x8 a[4], b[4];
    // -------- PH1 --------
#pragma unroll
    for (int i = 0; i < 4; ++i) a[i] = *(const bf16x8*)(base + aoff + i * 512);
#pragma unroll
    for (int j = 0; j < 4; ++j) b[j] = *(const bf16x8*)(base + 16384 + boff + j * 512);
    STAGE(Ab, t1 * 64 + 32, xbase + 8192);
    __builtin_amdgcn_s_barrier();
    asm volatile("s_waitcnt lgkmcnt(0)" ::: "memory");
    __builtin_amdgcn_sched_barrier(0);
    __builtin_amdgcn_s_setprio(1);
#pragma unroll
    for (int i = 0; i < 4; ++i)
#pragma unroll
      for (int j = 0; j < 4; ++j)
        acc[i][j] = __builtin_amdgcn_mfma_f32_16x16x32_bf16(a[i], b[j], acc[i][j], 0, 0, 0);
    __builtin_amdgcn_s_setprio(0);
    __builtin_amdgcn_s_barrier();

    // -------- PH2 --------
#pragma unroll
    for (int i = 0; i < 4; ++i) a[i] = *(const bf16x8*)(base + aoff + (i + 4) * 512);
    STAGE(Bb, t1 * 64 + 32, xbase + 24576);
    __builtin_amdgcn_s_barrier();
    asm volatile("s_waitcnt lgkmcnt(0)" ::: "memory");
    __builtin_amdgcn_sched_barrier(0);
    __builtin_amdgcn_s_setprio(1);
#pragma unroll
    for (int i = 0; i < 4; ++i)
#pragma unroll
      for (int j = 0; j < 4; ++j)
        acc[i + 4][j] = __builtin_amdgcn_mfma_f32_16x16x32_bf16(a[i], b[j], acc[i + 4][j], 0, 0, 0);
    __builtin_amdgcn_s_setprio(0);
    asm volatile("s_waitcnt vmcnt(8)" ::: "memory");
    __builtin_amdgcn_s_barrier();

    // -------- PH3 --------
#pragma unroll
    for (int i = 0; i < 4; ++i) a[i] = *(const bf16x8*)(base + 8192 + aoff + i * 512);
#pragma unroll
    for (int j = 0; j < 4; ++j) b[j] = *(const bf16x8*)(base + 24576 + boff + j * 512);
    STAGE(Ab, t2 * 64, base + 0);
    __builtin_amdgcn_s_barrier();
    asm volatile("s_waitcnt lgkmcnt(0)" ::: "memory");
    __builtin_amdgcn_sched_barrier(0);
    __builtin_amdgcn_s_setprio(1);
#pragma unroll
    for (int i = 0; i < 4; ++i)
#pragma unroll
      for (int j = 0; j < 4; ++j)
        acc[i][j] = __builtin_amdgcn_mfma_f32_16x16x32_bf16(a[i], b[j], acc[i][j], 0, 0, 0);
    __builtin_amdgcn_s_setprio(0);
    __builtin_amdgcn_s_barrier();

    // -------- PH4 --------
#pragma unroll
    for (int i = 0; i < 4; ++i) a[i] = *(const bf16x8*)(base + 8192 + aoff + (i + 4) * 512);
    STAGE(Bb, t2 * 64, base + 16384);
    __builtin_amdgcn_s_barrier();
    asm volatile("s_waitcnt lgkmcnt(0)" ::: "memory");
    __builtin_amdgcn_sched_barrier(0);
    __builtin_amdgcn_s_setprio(1);
#pragma unroll
    for (int i = 0; i < 4; ++i)
#pragma unroll
      for (int j = 0; j < 4; ++j)
        acc[i + 4][j] = __builtin_amdgcn_mfma_f32_16x16x32_bf16(a[i], b[j], acc[i + 4][j], 0, 0, 0);
    __builtin_amdgcn_s_setprio(0);
    asm volatile("s_waitcnt vmcnt(8)" ::: "memory");
    __builtin_amdgcn_s_barrier();
  }
#undef STAGE

  unsigned short* obase; int ldo, cb;
  if (n0 < 2048) { obase = qo; ldo = 2048; cb = n0; }
  else if (n0 < 3072) { obase = ko; ldo = 1024; cb = n0 - 2048; }
  else { obase = vo; ldo = 1024; cb = n0 - 3072; }
  const int rbase = m0 + wr * 128 + (lane >> 4) * 4;
  const int cbase = cb + wc * 64 + fm;
#pragma unroll
  for (int i = 0; i < 8; ++i)
#pragma unroll
    for (int j = 0; j < 4; ++j)
#pragma unroll
      for (int r = 0; r < 4; ++r)
        obase[(size_t)(rbase + i * 16 + r) * ldo + cbase + j * 16] = f2bf(acc[i][j][r]);
}

// ---------------------------------------------------------------------------
// m97-style bf16 MFMA GEMM core (16x16x32), 128x128 tile. (used by gemm_out)
// ---------------------------------------------------------------------------
__device__ __forceinline__ void gemm128_core(
    const unsigned short* __restrict__ A, const unsigned short* __restrict__ Bt,
    unsigned short* As, unsigned short* Bs, int m0, int n0, int K,
    f32x4 acc[4][4]) {
  const int tid = threadIdx.x;
  const int wave = tid >> 6, lane = tid & 63;
  const int wm = (wave & 1) << 6, wn = (wave >> 1) << 6;
  const int i0 = wave * 2, i1 = wave * 2 + 1;
  const int sr = lane >> 2;
  const int sc = (lane & 3) * 8;
  const size_t ar0 = (size_t)(m0 + i0 * 16 + sr) * K + sc;
  const size_t ar1 = (size_t)(m0 + i1 * 16 + sr) * K + sc;
  const size_t br0 = (size_t)(n0 + i0 * 16 + sr) * K + sc;
  const size_t br1 = (size_t)(n0 + i1 * 16 + sr) * K + sc;
  const int fm = lane & 15, fk = (lane >> 4) * 8;

  for (int kt = 0; kt < K; kt += 32) {
    GLD16(A + ar0 + kt, As + i0 * 512);
    GLD16(A + ar1 + kt, As + i1 * 512);
    GLD16(Bt + br0 + kt, Bs + i0 * 512);
    GLD16(Bt + br1 + kt, Bs + i1 * 512);
    __syncthreads();
    bf16x8 af[4], bv[4];
#pragma unroll
    for (int i = 0; i < 4; ++i)
      af[i] = *(const bf16x8*)&As[(wm + i * 16 + fm) * 32 + fk];
#pragma unroll
    for (int j = 0; j < 4; ++j)
      bv[j] = *(const bf16x8*)&Bs[(wn + j * 16 + fm) * 32 + fk];
#pragma unroll
    for (int i = 0; i < 4; ++i)
#pragma unroll
      for (int j = 0; j < 4; ++j)
        acc[i][j] = __builtin_amdgcn_mfma_f32_16x16x32_bf16(af[i], bv[j], acc[i][j], 0, 0, 0);
    __syncthreads();
  }
}

// Output projection: abuf(4096x2048 bf16) @ wot^T -> out fp32
__global__ __launch_bounds__(256) void gemm_out_bf16(
    const unsigned short* __restrict__ ab, const unsigned short* __restrict__ wot,
    float* __restrict__ out) {
  __shared__ unsigned short As[128 * 32];
  __shared__ unsigned short Bs[128 * 32];
  const int n0 = blockIdx.x * 128, m0 = blockIdx.y * 128;
  f32x4 acc[4][4];
#pragma unroll
  for (int i = 0; i < 4; ++i)
#pragma unroll
    for (int j = 0; j < 4; ++j) acc[i][j] = {0.f, 0.f, 0.f, 0.f};
  gemm128_core(ab, wot, As, Bs, m0, n0, 2048, acc);

  const int lane = threadIdx.x & 63, wave = threadIdx.x >> 6;
  const int wm = (wave & 1) << 6, wn = (wave >> 1) << 6;
  const int rbase = m0 + wm + (lane >> 4) * 4;
  const int cbase = n0 + wn + (lane & 15);
#pragma unroll
  for (int i = 0; i < 4; ++i)
#pragma unroll
    for (int j = 0; j < 4; ++j)
#pragma unroll
      for (int r = 0; r < 4; ++r)
        out[(size_t)(rbase + i * 16 + r) * 2048 + cbase + j * 16] = acc[i][j][r];
}

// ---------------------------------------------------------------------------
// postproc: fused RMSNorm+RoPE (q in-place, k -> fragment-major panels) +
// V panelize (fragment-major).
// K panel (per b,kvh,p=t/32), 8192 us: el = (h>>3)*256 + (t&31)*8 + (h&7).
//   attn QK^T B-frag: lane reads 16B at kc*512 + l5*256 + l31*8 ->
//   lane-linear 1 KB per dwordx4 instr, direct to VGPR.
// V panel (per b,kvh,p), 8192 us: el = (h>>5)*1024 + ((s>>3)&3)*256 + (h&31)*8 + (s&7).
//   attn PV B-frag: lane reads 16B at hb*1024 + (2j+l5)*256 + l31*8 ->
//   lane-linear 1 KB per dwordx4 instr.
// ---------------------------------------------------------------------------
__global__ __launch_bounds__(256) void postproc(
    unsigned short* __restrict__ qb, const unsigned short* __restrict__ kb,
    unsigned short* __restrict__ kpan,
    const unsigned short* __restrict__ vbf, unsigned short* __restrict__ vpan,
    const int* __restrict__ positions,
    const float* __restrict__ qns, const float* __restrict__ kns) {
  const int blk = blockIdx.x;
  const int tid = threadIdx.x;
  if (blk < 12288) {
    int row = blk * 4 + (tid >> 6);
    int lane = tid & 63;
    const unsigned short* src; const float* ns; float extra; int bt;
    bool isq = row < 32768;
    if (isq) {
      src = qb + (size_t)row * 256; ns = qns; extra = 0.0625f; bt = row >> 3;
    } else {
      int r = row - 32768;
      src = kb + (size_t)r * 256; ns = kns; extra = 1.0f; bt = r >> 2;
    }
    int pos = positions[bt];

    ushort4 u = *(const ushort4*)&src[lane << 2];
    float xv[4] = {bf2f(u.x), bf2f(u.y), bf2f(u.z), bf2f(u.w)};
    float ss = xv[0]*xv[0] + xv[1]*xv[1] + xv[2]*xv[2] + xv[3]*xv[3];
#pragma unroll
    for (int off = 1; off < 64; off <<= 1) ss += __shfl_xor(ss, off, 64);
    float rinv = rsqrtf(ss * (1.0f / 256.0f) + 1e-6f);

    float4 sc4 = *(const float4*)&ns[lane << 2];
    xv[0] *= rinv * (1.0f + sc4.x);
    xv[1] *= rinv * (1.0f + sc4.y);
    xv[2] *= rinv * (1.0f + sc4.z);
    xv[3] *= rinv * (1.0f + sc4.w);

    float ov[4];
#pragma unroll
    for (int c = 0; c < 4; ++c) ov[c] = __shfl_xor(xv[c], 32, 64);

    int hr = (lane & 31) << 2;
    float sgn = (lane < 32) ? -1.0f : 1.0f;
    ushort4 w4;
    unsigned short res[4];
#pragma unroll
    for (int c = 0; c < 4; ++c) {
      float invts = exp2f(-(float)(hr + c) * 0.10381025296523007f);
      float angle = (float)pos * invts;
      float sn, cs;
      __sincosf(angle, &sn, &cs);
      res[c] = f2bf((xv[c] * cs + sgn * ov[c] * sn) * extra);
    }
    w4.x = res[0]; w4.y = res[1]; w4.z = res[2]; w4.w = res[3];
    if (isq) {
      *(ushort4*)&qb[(size_t)row * 256 + (lane << 2)] = w4;
    } else {
      int r = row - 32768;
      int kvh = r & 3;
      int b_ = bt >> 11, t = bt & 2047;
      unsigned short* pan = kpan + (((size_t)(b_ * 4 + kvh) * 64 + (t >> 5)) * 8192);
      int s = t & 31;
      // h = lane*4 + c -> oct = lane>>1, off = (lane&1)*4 + c (contiguous u4)
      size_t el = (size_t)(lane >> 1) * 256 + (size_t)s * 8 + (lane & 1) * 4;
      *(ushort4*)&pan[el] = w4;
    }
    return;
  }
  // ---- V panelize ----
  __shared__ unsigned short tile[64][68];
  int idx = blk - 12288;
  int h0 = (idx & 3) * 64;
  int t0 = ((idx >> 2) & 31) * 64;
  int z = idx >> 7;  // b*4 + kvh
  int tx = tid & 15, ty = tid >> 4;
  const unsigned short* src = vbf + ((size_t)(z >> 2) * 8192 + (z & 3)) * 256;
#pragma unroll
  for (int p = 0; p < 4; ++p) {
    ushort4 v = *(const ushort4*)&src[(size_t)(t0 + ty + 16 * p) * 1024 + h0 + tx * 4];
    tile[ty + 16 * p][tx * 4 + 0] = v.x; tile[ty + 16 * p][tx * 4 + 1] = v.y;
    tile[ty + 16 * p][tx * 4 + 2] = v.z; tile[ty + 16 * p][tx * 4 + 3] = v.w;
  }
  __syncthreads();
#pragma unroll
  for (int p = 0; p < 4; ++p) {
    int hh = ty + 16 * p;
    int h = h0 + hh;
    int t = t0 + tx * 4;
    int pp = t >> 5, s = t & 31;
    ushort4 o;
    o.x = tile[tx * 4 + 0][hh]; o.y = tile[tx * 4 + 1][hh];
    o.z = tile[tx * 4 + 2][hh]; o.w = tile[tx * 4 + 3][hh];
    // el(h, s..s+3): (h>>5)*1024 + ((s>>3)&3)*256 + (h&31)*8 + (s&7), contiguous
    size_t el = ((size_t)z * 64 + pp) * 8192 + (size_t)(h >> 5) * 1024 +
                (size_t)((s >> 3) & 3) * 256 + (size_t)(h & 31) * 8 + (s & 7);
    *(ushort4*)&vpan[el] = o;
  }
}

// ---------------------------------------------------------------------------
// MFMA sliding-window attention, 32x32x16 bf16, static-max softmax.
// ONE WAVE per (b, kvh, head, t-tile): 1024 blocks x 64 threads, all resident.
// K/V read DIRECTLY into registers from fragment-major panels (coalesced
// 1 KB/dwordx4). No LDS staging, no barriers, no vmcnt drains: pure register
// dataflow. K double-buffered (prefetch t+1 during softmax/PV of t);
// V issued in two batches (batch0 before QK^T, batch1 after Ps write) to
// cap peak VGPR liveness (~430, no spill at the 512 cap).
// LDS = 3 KB wave-private Ps repack only. blockIdx&7 = (kvh,b) -> XCD L2.
// ---------------------------------------------------------------------------
__global__ __launch_bounds__(64, 1) void attn_mfma(
    const unsigned short* __restrict__ qb,    // [b][t][8][256]
    const unsigned short* __restrict__ kpan,  // frag-major K panels
    const unsigned short* __restrict__ vpan,  // frag-major V panels
    unsigned short* __restrict__ ob) {        // [b][t][8][256]
  __shared__ __align__(16) unsigned short Ps[1536];  // [half 2][m 32][24]

  const int lane = threadIdx.x & 63;
  const int l5 = lane >> 5, l31 = lane & 31;
  const int blk = blockIdx.x;
  const int pair = blk & 7;
  const int r = blk >> 3;          // 0..127
  const int tt = r & 63;
  const int head = r >> 6;         // 0..1
  const int kvh = pair >> 1, b = pair & 1;
  const int n = 2 * kvh + head;
  const int t0 = tt * 32;
  const int tmin = t0, tmax = t0 + 31;

  // Q fragments in registers (A-operand: m=l31 row, k-octet=l5)
  bf16x8 aq[16];
  {
    const unsigned short* qrow =
        qb + (((size_t)b * 2048 + tmin + l31) * 8 + n) * 256 + l5 * 8;
#pragma unroll
    for (int kc = 0; kc < 16; ++kc) aq[kc] = *(const bf16x8*)(qrow + kc * 16);
  }

  f32x16 O[8], lsum;
#pragma unroll
  for (int i = 0; i < 8; ++i)
#pragma unroll
    for (int rr = 0; rr < 16; ++rr) O[i][rr] = 0.f;
#pragma unroll
  for (int rr = 0; rr < 16; ++rr) lsum[rr] = 0.f;

  bf16x8 ones;
#pragma unroll
  for (int i = 0; i < 8; ++i) ones[i] = (short)0x3F80;  // bf16 1.0

  const unsigned short* kpb = kpan + (size_t)(b * 4 + kvh) * 64 * 8192;
  const unsigned short* vpb = vpan + (size_t)(b * 4 + kvh) * 64 * 8192;

  int s_lo = t0 - 1024; if (s_lo < 0) s_lo = 0;
  const int p0 = s_lo >> 5;
  const int nt = ((t0 + 32) - s_lo) >> 5;  // 1..33 tiles

  const int koff = l5 * 256 + l31 * 8;               // K frag: + kc*512
  const int voff0 = l5 * 256 + l31 * 8;              // V frag j=0: + hb*1024
  const int voff1 = (2 + l5) * 256 + l31 * 8;        // V frag j=1: + hb*1024

  bf16x8 KA[16], KB[16];

  // prologue: load K tile 0 into KA
  {
    const unsigned short* kp = kpb + (size_t)p0 * 8192;
#pragma unroll
    for (int u = 0; u < 16; ++u) KA[u] = *(const bf16x8*)(kp + u * 512 + koff);
  }

#define ATTN_BODY(CUR, NXT)                                                   \
  do {                                                                        \
    const int s0 = s_lo + it * 32;                                            \
    if (it + 1 < nt) { /* prefetch next K: full-step cover */                 \
      const unsigned short* kp = kpb + (size_t)(p0 + it + 1) * 8192;          \
      _Pragma("unroll")                                                       \
      for (int u = 0; u < 16; ++u) NXT[u] = *(const bf16x8*)(kp + u * 512 + koff); \
    }                                                                         \
    const unsigned short* vp = vpb + (size_t)(p0 + it) * 8192;                \
    bf16x8 Vv0[8], Vv1[8];                                                    \
    _Pragma("unroll") /* V batch0 (hb 0..3): cover = QK^T + softmax */        \
    for (int hb = 0; hb < 4; ++hb) {                                          \
      Vv0[hb * 2]     = *(const bf16x8*)(vp + hb * 1024 + voff0);             \
      Vv0[hb * 2 + 1] = *(const bf16x8*)(vp + hb * 1024 + voff1);             \
    }                                                                         \
    f32x16 pa, pb;                                                            \
    _Pragma("unroll")                                                         \
    for (int rr = 0; rr < 16; ++rr) { pa[rr] = 0.f; pb[rr] = 0.f; }           \
    _Pragma("unroll")                                                         \
    for (int kc = 0; kc < 16; kc += 2) {                                      \
      pa = __builtin_amdgcn_mfma_f32_32x32x16_bf16(aq[kc], CUR[kc], pa, 0, 0, 0); \
      pb = __builtin_amdgcn_mfma_f32_32x32x16_bf16(aq[kc + 1], CUR[kc + 1], pb, 0, 0, 0); \
    }                                                                         \
    bool allvalid = (s0 + 31 <= tmin) && (s0 >= tmax - 1023);                 \
    int scol = s0 + l31;                                                      \
    _Pragma("unroll")                                                         \
    for (int rr = 0; rr < 16; ++rr) {                                         \
      float sv = pa[rr] + pb[rr];                                             \
      float p = exp2f(sv * 1.442695040888963f);                               \
      int m = (rr & 3) + 8 * (rr >> 2) + 4 * l5;                              \
      if (!allvalid) {                                                        \
        int dt = (tmin + m) - scol;                                           \
        p = (dt >= 0 && dt < 1024) ? p : 0.f;                                 \
      }                                                                       \
      Ps[(l31 >> 4) * 768 + m * 24 + (l31 & 15)] = f2bf(p);                   \
    }                                                                         \
    _Pragma("unroll") /* V batch1 (hb 4..7): cover = lgkm wait + lsum + PV0 */\
    for (int hb = 4; hb < 8; ++hb) {                                          \
      Vv1[(hb - 4) * 2]     = *(const bf16x8*)(vp + hb * 1024 + voff0);       \
      Vv1[(hb - 4) * 2 + 1] = *(const bf16x8*)(vp + hb * 1024 + voff1);       \
    }                                                                         \
    bf16x8 pf0 = *(const bf16x8*)&Ps[l31 * 24 + l5 * 8];                      \
    bf16x8 pf1 = *(const bf16x8*)&Ps[768 + l31 * 24 + l5 * 8];                \
    lsum = __builtin_amdgcn_mfma_f32_32x32x16_bf16(pf0, ones, lsum, 0, 0, 0); \
    lsum = __builtin_amdgcn_mfma_f32_32x32x16_bf16(pf1, ones, lsum, 0, 0, 0); \
    _Pragma("unroll")                                                         \
    for (int hb = 0; hb < 4; ++hb) {                                          \
      O[hb] = __builtin_amdgcn_mfma_f32_32x32x16_bf16(pf0, Vv0[hb * 2], O[hb], 0, 0, 0); \
      O[hb] = __builtin_amdgcn_mfma_f32_32x32x16_bf16(pf1, Vv0[hb * 2 + 1], O[hb], 0, 0, 0); \
    }                                                                         \
    _Pragma("unroll")                                                         \
    for (int hb = 4; hb < 8; ++hb) {                                          \
      O[hb] = __builtin_amdgcn_mfma_f32_32x32x16_bf16(pf0, Vv1[(hb - 4) * 2], O[hb], 0, 0, 0); \
      O[hb] = __builtin_amdgcn_mfma_f32_32x32x16_bf16(pf1, Vv1[(hb - 4) * 2 + 1], O[hb], 0, 0, 0); \
    }                                                                         \
  } while (0)

  int it = 0;
  while (true) {
    ATTN_BODY(KA, KB);
    if (++it == nt) break;
    ATTN_BODY(KB, KA);
    if (++it == nt) break;
  }
#undef ATTN_BODY

  // epilogue: normalize and store bf16
  unsigned short* obase = ob + (((size_t)b * 2048 + tmin) * 8 + n) * 256;
#pragma unroll
  for (int rr = 0; rr < 16; ++rr) {
    int m = (rr & 3) + 8 * (rr >> 2) + 4 * l5;
    float rinv = 1.0f / lsum[rr];
    size_t rowoff = (size_t)m * 2048;
#pragma unroll
    for (int hb = 0; hb < 8; ++hb)
      obase[rowoff + hb * 32 + l31] = f2bf(O[hb][rr] * rinv);
  }
}

extern "C" void kernel_launch(void* const* d_in, const int* in_sizes, int n_in,
                              void* d_out, int out_size, void* d_ws, size_t ws_size,
                              hipStream_t stream) {
  const float* x   = (const float*)d_in[0];
  const int* pos   = (const int*)d_in[1];
  const float* q_w = (const float*)d_in[2];
  const float* k_w = (const float*)d_in[3];
  const float* v_w = (const float*)d_in[4];
  const float* o_w = (const float*)d_in[5];
  const float* qns = (const float*)d_in[6];
  const float* kns = (const float*)d_in[7];
  float* out = (float*)d_out;

  unsigned short* W = (unsigned short*)d_ws;
  unsigned short* qb0   = W;               //  8,388,608 us  q bf16
  unsigned short* kb0   = W + 8388608;     //  4,194,304 us  k bf16 (row-major)
  unsigned short* vbf   = W + 12582912;    //  4,194,304 us  v bf16 (row-major)
  unsigned short* vpan  = W + 16777216;    //  4,194,304 us  v panels (frag-major)
  unsigned short* kpan  = W + 20971520;    //  4,194,304 us  k panels (frag-major)
  unsigned short* xb    = W + 25165824;    //  8,388,608 us  x bf16
  unsigned short* wqkvt = W + 33554432;    //  8,388,608 us  qkv weights^T
  unsigned short* abuf  = wqkvt;           //  reuse after gemm_qkv
  unsigned short* wot   = W + 41943040;    //  4,194,304 us  o weights^T
  // total 46,137,344 us = 92.3 MB

  prep<<<dim3(11264), 256, 0, stream>>>(x, q_w, k_w, v_w, o_w, xb, wqkvt, wot);
  gemm_qkv_256<<<dim3(256), 512, 0, stream>>>(xb, wqkvt, qb0, kb0, vbf);
  postproc<<<dim3(13312), 256, 0, stream>>>(qb0, kb0, kpan, vbf, vpan, pos, qns, kns);
  attn_mfma<<<dim3(1024), 64, 0, stream>>>(qb0, kpan, vpan, abuf);
  gemm_out_bf16<<<dim3(16, 32), 256, 0, stream>>>(abuf, wot, out);
}

// Round 6
// 346.404 us; speedup vs baseline: 1.5382x; 1.5382x over previous
//
#include <hip/hip_runtime.h>
#include <cmath>

#define T_SEQ 2048
#define WINDOW 1024

typedef __attribute__((ext_vector_type(8))) short bf16x8;
typedef __attribute__((ext_vector_type(4))) float f32x4;
typedef __attribute__((ext_vector_type(16))) float f32x16;

__device__ __forceinline__ unsigned short f2bf(float f) {
  union { float f; unsigned int u; } v; v.f = f;
  unsigned int r = v.u + 0x7FFFu + ((v.u >> 16) & 1u);  // RNE
  return (unsigned short)(r >> 16);
}
__device__ __forceinline__ float bf2f(unsigned short u) {
  union { unsigned int i; float f; } v; v.i = ((unsigned int)u) << 16;
  return v.f;
}

#define GLD16(gp, lp)                                                  \
  __builtin_amdgcn_global_load_lds(                                    \
      (__attribute__((address_space(1))) unsigned int*)(gp),           \
      (__attribute__((address_space(3))) unsigned int*)(lp), 16, 0, 0)

// ---------------------------------------------------------------------------
// prep: fused cast_bf16(x) + transpose_wqkv + transpose_wo.
// ---------------------------------------------------------------------------
__global__ __launch_bounds__(256) void prep(
    const float* __restrict__ x,
    const float* __restrict__ qw, const float* __restrict__ kw,
    const float* __restrict__ vw, const float* __restrict__ ow,
    unsigned short* __restrict__ xb, unsigned short* __restrict__ wqkvt,
    unsigned short* __restrict__ wot) {
  __shared__ float tile[64][65];
  const int blk = blockIdx.x;
  const int tid = threadIdx.x;
  if (blk < 8192) {
    size_t i = (size_t)blk * 256 + tid;
    float4 v = *(const float4*)&x[i * 4];
    ushort4 o;
    o.x = f2bf(v.x); o.y = f2bf(v.y); o.z = f2bf(v.z); o.w = f2bf(v.w);
    *(ushort4*)&xb[i * 4] = o;
    return;
  }
  int tx = tid & 15, ty = tid >> 4;
  if (blk < 10240) {
    int idx = blk - 8192;
    int c0 = (idx & 63) * 64, d0 = (idx >> 6) * 64;
    const float* src; int hbase;
    if (c0 < 2048) { src = qw + (size_t)(c0 >> 8) * 524288; hbase = c0 & 255; }
    else if (c0 < 3072) { int cc = c0 - 2048; src = kw + (size_t)(cc >> 8) * 524288; hbase = cc & 255; }
    else { int cc = c0 - 3072; src = vw + (size_t)(cc >> 8) * 524288; hbase = cc & 255; }
#pragma unroll
    for (int p = 0; p < 4; ++p) {
      float4 v = *(const float4*)&src[(size_t)(d0 + ty + 16 * p) * 256 + hbase + tx * 4];
      tile[ty + 16 * p][tx * 4 + 0] = v.x; tile[ty + 16 * p][tx * 4 + 1] = v.y;
      tile[ty + 16 * p][tx * 4 + 2] = v.z; tile[ty + 16 * p][tx * 4 + 3] = v.w;
    }
    __syncthreads();
#pragma unroll
    for (int p = 0; p < 4; ++p) {
      int hh = ty + 16 * p;
      ushort4 o;
      o.x = f2bf(tile[tx * 4 + 0][hh]); o.y = f2bf(tile[tx * 4 + 1][hh]);
      o.z = f2bf(tile[tx * 4 + 2][hh]); o.w = f2bf(tile[tx * 4 + 3][hh]);
      *(ushort4*)&wqkvt[(size_t)(c0 + hh) * 2048 + d0 + tx * 4] = o;
    }
  } else {
    int idx = blk - 10240;
    int j0 = (idx & 31) * 64, d0 = (idx >> 5) * 64;
#pragma unroll
    for (int p = 0; p < 4; ++p) {
      float4 v = *(const float4*)&ow[(size_t)(j0 + ty + 16 * p) * 2048 + d0 + tx * 4];
      tile[ty + 16 * p][tx * 4 + 0] = v.x; tile[ty + 16 * p][tx * 4 + 1] = v.y;
      tile[ty + 16 * p][tx * 4 + 2] = v.z; tile[ty + 16 * p][tx * 4 + 3] = v.w;
    }
    __syncthreads();
#pragma unroll
    for (int p = 0; p < 4; ++p) {
      int hh = ty + 16 * p;
      ushort4 o;
      o.x = f2bf(tile[tx * 4 + 0][hh]); o.y = f2bf(tile[tx * 4 + 1][hh]);
      o.z = f2bf(tile[tx * 4 + 2][hh]); o.w = f2bf(tile[tx * 4 + 3][hh]);
      *(ushort4*)&wot[(size_t)(d0 + hh) * 2048 + j0 + tx * 4] = o;
    }
  }
}

// ---------------------------------------------------------------------------
// 256x256-tile 8-phase bf16 MFMA GEMM core (T1+T2+T3+T4+T5).
// Used by gemm_qkv_256 (grid 256) and gemm_out_256 (grid 128).
// ---------------------------------------------------------------------------
__device__ __forceinline__ void gemm256_core(
    const unsigned short* __restrict__ Ab, const unsigned short* __restrict__ Bb,
    unsigned short* lds, f32x4 acc[8][4], int aoff, int boff) {
  const int tid = threadIdx.x;

  const int l0 = tid, l1 = tid + 512;
  const int r0 = l0 >> 2, o0 = l0 & 3;
  const int r1 = l1 >> 2, o1 = l1 & 3;
  const int sA0 = r0 * 2048 + ((o0 ^ ((r0 >> 2) & 3)) << 3);
  const int sA1 = r1 * 2048 + ((o1 ^ ((r1 >> 2) & 3)) << 3);

#define STAGE(srcbase, kofs, dstbase)                  \
  do {                                                 \
    GLD16((srcbase) + sA0 + (kofs), (dstbase) + l0 * 8); \
    GLD16((srcbase) + sA1 + (kofs), (dstbase) + l1 * 8); \
  } while (0)

  STAGE(Ab, 0,  lds + 0);
  STAGE(Bb, 0,  lds + 16384);
  STAGE(Ab, 32, lds + 8192);
  STAGE(Bb, 32, lds + 24576);
  STAGE(Ab, 64, lds + 32768);
  STAGE(Bb, 64, lds + 49152);
  asm volatile("s_waitcnt vmcnt(8)" ::: "memory");
  __builtin_amdgcn_s_barrier();

  for (int t = 0; t < 32; ++t) {
    const int p = t & 1;
    unsigned short* base = lds + p * 32768;
    unsigned short* xbase = lds + (p ^ 1) * 32768;
    const int t1 = (t < 31) ? t + 1 : 31;
    const int t2 = (t < 30) ? t + 2 : 31;

    bf16x8 a[4], b[4];
    // -------- PH1 --------
#pragma unroll
    for (int i = 0; i < 4; ++i) a[i] = *(const bf16x8*)(base + aoff + i * 512);
#pragma unroll
    for (int j = 0; j < 4; ++j) b[j] = *(const bf16x8*)(base + 16384 + boff + j * 512);
    STAGE(Ab, t1 * 64 + 32, xbase + 8192);
    __builtin_amdgcn_s_barrier();
    asm volatile("s_waitcnt lgkmcnt(0)" ::: "memory");
    __builtin_amdgcn_sched_barrier(0);
    __builtin_amdgcn_s_setprio(1);
#pragma unroll
    for (int i = 0; i < 4; ++i)
#pragma unroll
      for (int j = 0; j < 4; ++j)
        acc[i][j] = __builtin_amdgcn_mfma_f32_16x16x32_bf16(a[i], b[j], acc[i][j], 0, 0, 0);
    __builtin_amdgcn_s_setprio(0);
    __builtin_amdgcn_s_barrier();

    // -------- PH2 --------
#pragma unroll
    for (int i = 0; i < 4; ++i) a[i] = *(const bf16x8*)(base + aoff + (i + 4) * 512);
    STAGE(Bb, t1 * 64 + 32, xbase + 24576);
    __builtin_amdgcn_s_barrier();
    asm volatile("s_waitcnt lgkmcnt(0)" ::: "memory");
    __builtin_amdgcn_sched_barrier(0);
    __builtin_amdgcn_s_setprio(1);
#pragma unroll
    for (int i = 0; i < 4; ++i)
#pragma unroll
      for (int j = 0; j < 4; ++j)
        acc[i + 4][j] = __builtin_amdgcn_mfma_f32_16x16x32_bf16(a[i], b[j], acc[i + 4][j], 0, 0, 0);
    __builtin_amdgcn_s_setprio(0);
    asm volatile("s_waitcnt vmcnt(8)" ::: "memory");
    __builtin_amdgcn_s_barrier();

    // -------- PH3 --------
#pragma unroll
    for (int i = 0; i < 4; ++i) a[i] = *(const bf16x8*)(base + 8192 + aoff + i * 512);
#pragma unroll
    for (int j = 0; j < 4; ++j) b[j] = *(const bf16x8*)(base + 24576 + boff + j * 512);
    STAGE(Ab, t2 * 64, base + 0);
    __builtin_amdgcn_s_barrier();
    asm volatile("s_waitcnt lgkmcnt(0)" ::: "memory");
    __builtin_amdgcn_sched_barrier(0);
    __builtin_amdgcn_s_setprio(1);
#pragma unroll
    for (int i = 0; i < 4; ++i)
#pragma unroll
      for (int j = 0; j < 4; ++j)
        acc[i][j] = __builtin_amdgcn_mfma_f32_16x16x32_bf16(a[i], b[j], acc[i][j], 0, 0, 0);
    __builtin_amdgcn_s_setprio(0);
    __builtin_amdgcn_s_barrier();

    // -------- PH4 --------
#pragma unroll
    for (int i = 0; i < 4; ++i) a[i] = *(const bf16x8*)(base + 8192 + aoff + (i + 4) * 512);
    STAGE(Bb, t2 * 64, base + 16384);
    __builtin_amdgcn_s_barrier();
    asm volatile("s_waitcnt lgkmcnt(0)" ::: "memory");
    __builtin_amdgcn_sched_barrier(0);
    __builtin_amdgcn_s_setprio(1);
#pragma unroll
    for (int i = 0; i < 4; ++i)
#pragma unroll
      for (int j = 0; j < 4; ++j)
        acc[i + 4][j] = __builtin_amdgcn_mfma_f32_16x16x32_bf16(a[i], b[j], acc[i + 4][j], 0, 0, 0);
    __builtin_amdgcn_s_setprio(0);
    asm volatile("s_waitcnt vmcnt(8)" ::: "memory");
    __builtin_amdgcn_s_barrier();
  }
#undef STAGE
}

// QKV projection: xb(4096x2048) @ wqkvt^T(4096x2048) -> q/k/v bf16
__global__ __launch_bounds__(512) void gemm_qkv_256(
    const unsigned short* __restrict__ xb, const unsigned short* __restrict__ wt,
    unsigned short* __restrict__ qo, unsigned short* __restrict__ ko,
    unsigned short* __restrict__ vo) {
  __shared__ unsigned short lds[65536];  // 128 KB
  const int tid = threadIdx.x;
  const int wave = tid >> 6, lane = tid & 63;
  const int wr = wave >> 2, wc = wave & 3;
  const int fm = lane & 15, fk = lane >> 4;

  const int bid = blockIdx.x;
  const int swz = (bid & 7) * 32 + (bid >> 3);  // nwg=256, bijective
  const int m0 = (swz >> 4) * 256, n0 = (swz & 15) * 256;

  const int soff = fm * 32 + ((fk ^ ((fm >> 2) & 3)) << 3);
  const int aoff = wr * 4096 + soff;
  const int boff = wc * 2048 + soff;

  f32x4 acc[8][4];
#pragma unroll
  for (int i = 0; i < 8; ++i)
#pragma unroll
    for (int j = 0; j < 4; ++j) acc[i][j] = {0.f, 0.f, 0.f, 0.f};

  gemm256_core(xb + (size_t)m0 * 2048, wt + (size_t)n0 * 2048, lds, acc, aoff, boff);

  unsigned short* obase; int ldo, cb;
  if (n0 < 2048) { obase = qo; ldo = 2048; cb = n0; }
  else if (n0 < 3072) { obase = ko; ldo = 1024; cb = n0 - 2048; }
  else { obase = vo; ldo = 1024; cb = n0 - 3072; }
  const int rbase = m0 + wr * 128 + (lane >> 4) * 4;
  const int cbase = cb + wc * 64 + fm;
#pragma unroll
  for (int i = 0; i < 8; ++i)
#pragma unroll
    for (int j = 0; j < 4; ++j)
#pragma unroll
      for (int r = 0; r < 4; ++r)
        obase[(size_t)(rbase + i * 16 + r) * ldo + cbase + j * 16] = f2bf(acc[i][j][r]);
}

// Output projection: abuf(4096x2048 bf16) @ wot^T -> out fp32. Grid 128.
__global__ __launch_bounds__(512) void gemm_out_256(
    const unsigned short* __restrict__ ab, const unsigned short* __restrict__ wot,
    float* __restrict__ out) {
  __shared__ unsigned short lds[65536];  // 128 KB
  const int tid = threadIdx.x;
  const int wave = tid >> 6, lane = tid & 63;
  const int wr = wave >> 2, wc = wave & 3;
  const int fm = lane & 15, fk = lane >> 4;

  const int bid = blockIdx.x;
  const int swz = (bid & 7) * 16 + (bid >> 3);  // nwg=128, bijective
  const int m0 = (swz >> 3) * 256, n0 = (swz & 7) * 256;

  const int soff = fm * 32 + ((fk ^ ((fm >> 2) & 3)) << 3);
  const int aoff = wr * 4096 + soff;
  const int boff = wc * 2048 + soff;

  f32x4 acc[8][4];
#pragma unroll
  for (int i = 0; i < 8; ++i)
#pragma unroll
    for (int j = 0; j < 4; ++j) acc[i][j] = {0.f, 0.f, 0.f, 0.f};

  gemm256_core(ab + (size_t)m0 * 2048, wot + (size_t)n0 * 2048, lds, acc, aoff, boff);

  const int rbase = m0 + wr * 128 + (lane >> 4) * 4;
  const int cbase = n0 + wc * 64 + fm;
#pragma unroll
  for (int i = 0; i < 8; ++i)
#pragma unroll
    for (int j = 0; j < 4; ++j)
#pragma unroll
      for (int r = 0; r < 4; ++r)
        out[(size_t)(rbase + i * 16 + r) * 2048 + cbase + j * 16] = acc[i][j][r];
}

// ---------------------------------------------------------------------------
// postproc: fused RMSNorm+RoPE (q in-place, k -> swizzled panels) + V panelize.
// K panel layout (per b,kvh,p=t/32): [s=t%32][chunk c^s][16B] — the attention
// LDS image; attn staging is an identity coalesced copy.
// V panel chunk key g(h) = (h ^ (h>>2)) & 3 (bank-conflict-reduced pair with
// the attn PV read; r2/r3-validated).
// ---------------------------------------------------------------------------
__global__ __launch_bounds__(256) void postproc(
    unsigned short* __restrict__ qb, const unsigned short* __restrict__ kb,
    unsigned short* __restrict__ kpan,
    const unsigned short* __restrict__ vbf, unsigned short* __restrict__ vpan,
    const int* __restrict__ positions,
    const float* __restrict__ qns, const float* __restrict__ kns) {
  const int blk = blockIdx.x;
  const int tid = threadIdx.x;
  if (blk < 12288) {
    int row = blk * 4 + (tid >> 6);
    int lane = tid & 63;
    const unsigned short* src; const float* ns; float extra; int bt;
    bool isq = row < 32768;
    if (isq) {
      src = qb + (size_t)row * 256; ns = qns; extra = 0.0625f; bt = row >> 3;
    } else {
      int r = row - 32768;
      src = kb + (size_t)r * 256; ns = kns; extra = 1.0f; bt = r >> 2;
    }
    int pos = positions[bt];

    ushort4 u = *(const ushort4*)&src[lane << 2];
    float xv[4] = {bf2f(u.x), bf2f(u.y), bf2f(u.z), bf2f(u.w)};
    float ss = xv[0]*xv[0] + xv[1]*xv[1] + xv[2]*xv[2] + xv[3]*xv[3];
#pragma unroll
    for (int off = 1; off < 64; off <<= 1) ss += __shfl_xor(ss, off, 64);
    float rinv = rsqrtf(ss * (1.0f / 256.0f) + 1e-6f);

    float4 sc4 = *(const float4*)&ns[lane << 2];
    xv[0] *= rinv * (1.0f + sc4.x);
    xv[1] *= rinv * (1.0f + sc4.y);
    xv[2] *= rinv * (1.0f + sc4.z);
    xv[3] *= rinv * (1.0f + sc4.w);

    float ov[4];
#pragma unroll
    for (int c = 0; c < 4; ++c) ov[c] = __shfl_xor(xv[c], 32, 64);

    int hr = (lane & 31) << 2;
    float sgn = (lane < 32) ? -1.0f : 1.0f;
    ushort4 w4;
    unsigned short res[4];
#pragma unroll
    for (int c = 0; c < 4; ++c) {
      float invts = exp2f(-(float)(hr + c) * 0.10381025296523007f);
      float angle = (float)pos * invts;
      float sn, cs;
      __sincosf(angle, &sn, &cs);
      res[c] = f2bf((xv[c] * cs + sgn * ov[c] * sn) * extra);
    }
    w4.x = res[0]; w4.y = res[1]; w4.z = res[2]; w4.w = res[3];
    if (isq) {
      *(ushort4*)&qb[(size_t)row * 256 + (lane << 2)] = w4;
    } else {
      int r = row - 32768;
      int kvh = r & 3;
      int b_ = bt >> 11, t = bt & 2047;
      unsigned short* pan = kpan + (((size_t)(b_ * 4 + kvh) * 64 + (t >> 5)) * 8192);
      int s = t & 31;
      int c = lane >> 1;
      size_t el = (size_t)s * 256 + (size_t)((c ^ s) & 31) * 8 + (lane & 1) * 4;
      *(ushort4*)&pan[el] = w4;
    }
    return;
  }
  // ---- V panelize ----
  __shared__ unsigned short tile[64][68];
  int idx = blk - 12288;
  int h0 = (idx & 3) * 64;
  int t0 = ((idx >> 2) & 31) * 64;
  int z = idx >> 7;  // b*4 + kvh
  int tx = tid & 15, ty = tid >> 4;
  const unsigned short* src = vbf + ((size_t)(z >> 2) * 8192 + (z & 3)) * 256;
#pragma unroll
  for (int p = 0; p < 4; ++p) {
    ushort4 v = *(const ushort4*)&src[(size_t)(t0 + ty + 16 * p) * 1024 + h0 + tx * 4];
    tile[ty + 16 * p][tx * 4 + 0] = v.x; tile[ty + 16 * p][tx * 4 + 1] = v.y;
    tile[ty + 16 * p][tx * 4 + 2] = v.z; tile[ty + 16 * p][tx * 4 + 3] = v.w;
  }
  __syncthreads();
#pragma unroll
  for (int p = 0; p < 4; ++p) {
    int hh = ty + 16 * p;
    int h = h0 + hh;
    int t = t0 + tx * 4;
    int pp = t >> 5, s = t & 31;
    ushort4 o;
    o.x = tile[tx * 4 + 0][hh]; o.y = tile[tx * 4 + 1][hh];
    o.z = tile[tx * 4 + 2][hh]; o.w = tile[tx * 4 + 3][hh];
    size_t el = ((size_t)z * 64 + pp) * 8192 + (size_t)h * 32 +
                (size_t)(((s >> 3) ^ h ^ (h >> 2)) & 3) * 8 + (s & 7);
    *(ushort4*)&vpan[el] = o;
  }
}

// ---------------------------------------------------------------------------
// MFMA sliding-window attention, 32x32x16 bf16, static-max softmax.
// Round-1 structure (best measured: 87.5 us): block = 128 thr = 2 waves,
// wave w -> head 2*kvh + w, q-rows [t0, t0+32). K/V staged from pre-swizzled
// 16 KB panels: identity, fully-coalesced GLD16. 512 blocks = 2/CU.
// Only delta vs round 1: V chunk key gh = (row^(row>>2))&3 (conflict fix,
// writer+reader changed together; r2/r3-validated).
// ---------------------------------------------------------------------------
__global__ __launch_bounds__(128) void attn_mfma(
    const unsigned short* __restrict__ qb,    // [b][t][8][256]
    const unsigned short* __restrict__ kpan,  // [b*4+kvh][p][32 s][swz 512B]
    const unsigned short* __restrict__ vpan,  // [b*4+kvh][p][256 h][swz 64B]
    unsigned short* __restrict__ ob) {        // [b][t][8][256]
  __shared__ __align__(16) unsigned short Kl[8192];  // [s 32][chunk 32][8]
  __shared__ __align__(16) unsigned short Vl[8192];  // [h 256][chunk 4][8]
  __shared__ __align__(16) unsigned short Ps[3072];  // [w][half 2][m 32][24]

  const int tid = threadIdx.x;
  const int w = tid >> 6, lane = tid & 63;
  const int l5 = lane >> 5, l31 = lane & 31;
  const int pair = blockIdx.x & 7;
  const int t0 = (blockIdx.x >> 3) * 32;
  const int kvh = pair >> 1, b = pair & 1;
  const int n = 2 * kvh + w;
  const int tmin = t0, tmax = t0 + 31;

  // Q fragments in registers (A-operand: m=l31 row, k-octet=l5)
  bf16x8 aq[16];
  {
    const unsigned short* qrow =
        qb + (((size_t)b * 2048 + tmin + l31) * 8 + n) * 256 + l5 * 8;
#pragma unroll
    for (int kc = 0; kc < 16; ++kc) aq[kc] = *(const bf16x8*)(qrow + kc * 16);
  }

  f32x16 O[8], lsum;
#pragma unroll
  for (int i = 0; i < 8; ++i)
#pragma unroll
    for (int r = 0; r < 16; ++r) O[i][r] = 0.f;
#pragma unroll
  for (int r = 0; r < 16; ++r) lsum[r] = 0.f;

  bf16x8 ones;
#pragma unroll
  for (int i = 0; i < 8; ++i) ones[i] = (short)0x3F80;  // bf16 1.0

  const unsigned short* kpb = kpan + (size_t)(b * 4 + kvh) * 64 * 8192;
  const unsigned short* vpb = vpan + (size_t)(b * 4 + kvh) * 64 * 8192;

  int s_lo = t0 - 1024; if (s_lo < 0) s_lo = 0;
  const int s_end = t0 + 32;

  for (int s0 = s_lo; s0 < s_end; s0 += 32) {
    __syncthreads();  // both waves done reading Kl/Vl from previous step
    const unsigned short* kp = kpb + (size_t)(s0 >> 5) * 8192;
    const unsigned short* vp = vpb + (size_t)(s0 >> 5) * 8192;
#pragma unroll
    for (int j = 0; j < 8; ++j) {
      int g = j * 128 + tid;
      GLD16(kp + g * 8, Kl + g * 8);
    }
#pragma unroll
    for (int j = 0; j < 8; ++j) {
      int g = j * 128 + tid;
      GLD16(vp + g * 8, Vl + g * 8);
    }
    __syncthreads();  // staging complete

    // S = Q K^T (two parallel accumulation chains)
    f32x16 pa, pb;
#pragma unroll
    for (int r = 0; r < 16; ++r) { pa[r] = 0.f; pb[r] = 0.f; }
#pragma unroll
    for (int kc = 0; kc < 16; kc += 2) {
      bf16x8 b0 = *(const bf16x8*)&Kl[l31 * 256 + (((kc * 2 + l5) ^ l31) & 31) * 8];
      bf16x8 b1 = *(const bf16x8*)&Kl[l31 * 256 + ((((kc + 1) * 2 + l5) ^ l31) & 31) * 8];
      pa = __builtin_amdgcn_mfma_f32_32x32x16_bf16(aq[kc], b0, pa, 0, 0, 0);
      pb = __builtin_amdgcn_mfma_f32_32x32x16_bf16(aq[kc + 1], b1, pb, 0, 0, 0);
    }

    bool allvalid = (s0 + 31 <= tmin) && (s0 >= tmax - 1023);
    int scol = s0 + l31;
    // P = exp(S), mask -> 0; write to Ps as bf16 (A-layout, wave-private)
#pragma unroll
    for (int r = 0; r < 16; ++r) {
      float sv = pa[r] + pb[r];
      float p = exp2f(sv * 1.442695040888963f);
      int m = (r & 3) + 8 * (r >> 2) + 4 * l5;
      if (!allvalid) {
        int dt = (tmin + m) - scol;
        p = (dt >= 0 && dt < 1024) ? p : 0.f;
      }
      Ps[w * 1536 + (l31 >> 4) * 768 + m * 24 + (l31 & 15)] = f2bf(p);
    }

    // PV + row-sum (wave-private Ps: no barrier needed)
    bf16x8 pf0 = *(const bf16x8*)&Ps[w * 1536 + l31 * 24 + l5 * 8];
    bf16x8 pf1 = *(const bf16x8*)&Ps[w * 1536 + 768 + l31 * 24 + l5 * 8];
    lsum = __builtin_amdgcn_mfma_f32_32x32x16_bf16(pf0, ones, lsum, 0, 0, 0);
    lsum = __builtin_amdgcn_mfma_f32_32x32x16_bf16(pf1, ones, lsum, 0, 0, 0);
#pragma unroll
    for (int hb = 0; hb < 8; ++hb) {
      int row = hb * 32 + l31;
      int gh = (row ^ (row >> 2)) & 3;
      bf16x8 v0 = *(const bf16x8*)&Vl[row * 32 + ((l5 ^ gh) & 3) * 8];
      bf16x8 v1 = *(const bf16x8*)&Vl[row * 32 + (((2 + l5) ^ gh) & 3) * 8];
      O[hb] = __builtin_amdgcn_mfma_f32_32x32x16_bf16(pf0, v0, O[hb], 0, 0, 0);
      O[hb] = __builtin_amdgcn_mfma_f32_32x32x16_bf16(pf1, v1, O[hb], 0, 0, 0);
    }
  }

  // epilogue: normalize and store bf16
  unsigned short* obase = ob + (((size_t)b * 2048 + tmin) * 8 + n) * 256;
#pragma unroll
  for (int r = 0; r < 16; ++r) {
    int m = (r & 3) + 8 * (r >> 2) + 4 * l5;
    float rinv = 1.0f / lsum[r];
    size_t rowoff = (size_t)m * 2048;
#pragma unroll
    for (int hb = 0; hb < 8; ++hb)
      obase[rowoff + hb * 32 + l31] = f2bf(O[hb][r] * rinv);
  }
}

extern "C" void kernel_launch(void* const* d_in, const int* in_sizes, int n_in,
                              void* d_out, int out_size, void* d_ws, size_t ws_size,
                              hipStream_t stream) {
  const float* x   = (const float*)d_in[0];
  const int* pos   = (const int*)d_in[1];
  const float* q_w = (const float*)d_in[2];
  const float* k_w = (const float*)d_in[3];
  const float* v_w = (const float*)d_in[4];
  const float* o_w = (const float*)d_in[5];
  const float* qns = (const float*)d_in[6];
  const float* kns = (const float*)d_in[7];
  float* out = (float*)d_out;

  unsigned short* W = (unsigned short*)d_ws;
  unsigned short* qb0   = W;               //  8,388,608 us  q bf16
  unsigned short* kb0   = W + 8388608;     //  4,194,304 us  k bf16 (row-major)
  unsigned short* vbf   = W + 12582912;    //  4,194,304 us  v bf16 (row-major)
  unsigned short* vpan  = W + 16777216;    //  4,194,304 us  v panels (swizzled)
  unsigned short* kpan  = W + 20971520;    //  4,194,304 us  k panels (swizzled)
  unsigned short* xb    = W + 25165824;    //  8,388,608 us  x bf16
  unsigned short* wqkvt = W + 33554432;    //  8,388,608 us  qkv weights^T
  unsigned short* abuf  = wqkvt;           //  reuse after gemm_qkv
  unsigned short* wot   = W + 41943040;    //  4,194,304 us  o weights^T
  // total 46,137,344 us = 92.3 MB

  prep<<<dim3(11264), 256, 0, stream>>>(x, q_w, k_w, v_w, o_w, xb, wqkvt, wot);
  gemm_qkv_256<<<dim3(256), 512, 0, stream>>>(xb, wqkvt, qb0, kb0, vbf);
  postproc<<<dim3(13312), 256, 0, stream>>>(qb0, kb0, kpan, vbf, vpan, pos, qns, kns);
  attn_mfma<<<dim3(512), 128, 0, stream>>>(qb0, kpan, vpan, abuf);
  gemm_out_256<<<dim3(128), 512, 0, stream>>>(abuf, wot, out);
}

// Round 7
// 335.034 us; speedup vs baseline: 1.5905x; 1.0339x over previous
//
#include <hip/hip_runtime.h>
#include <cmath>

#define T_SEQ 2048
#define WINDOW 1024

typedef __attribute__((ext_vector_type(8))) short bf16x8;
typedef __attribute__((ext_vector_type(4))) float f32x4;
typedef __attribute__((ext_vector_type(16))) float f32x16;

__device__ __forceinline__ unsigned short f2bf(float f) {
  union { float f; unsigned int u; } v; v.f = f;
  unsigned int r = v.u + 0x7FFFu + ((v.u >> 16) & 1u);  // RNE
  return (unsigned short)(r >> 16);
}
__device__ __forceinline__ float bf2f(unsigned short u) {
  union { unsigned int i; float f; } v; v.i = ((unsigned int)u) << 16;
  return v.f;
}

#define GLD16(gp, lp)                                                  \
  __builtin_amdgcn_global_load_lds(                                    \
      (__attribute__((address_space(1))) unsigned int*)(gp),           \
      (__attribute__((address_space(3))) unsigned int*)(lp), 16, 0, 0)

// ---------------------------------------------------------------------------
// prep: fused cast_bf16(x) + transpose_wqkv + transpose_wo.
// ---------------------------------------------------------------------------
__global__ __launch_bounds__(256) void prep(
    const float* __restrict__ x,
    const float* __restrict__ qw, const float* __restrict__ kw,
    const float* __restrict__ vw, const float* __restrict__ ow,
    unsigned short* __restrict__ xb, unsigned short* __restrict__ wqkvt,
    unsigned short* __restrict__ wot) {
  __shared__ float tile[64][65];
  const int blk = blockIdx.x;
  const int tid = threadIdx.x;
  if (blk < 8192) {
    size_t i = (size_t)blk * 256 + tid;
    float4 v = *(const float4*)&x[i * 4];
    ushort4 o;
    o.x = f2bf(v.x); o.y = f2bf(v.y); o.z = f2bf(v.z); o.w = f2bf(v.w);
    *(ushort4*)&xb[i * 4] = o;
    return;
  }
  int tx = tid & 15, ty = tid >> 4;
  if (blk < 10240) {
    int idx = blk - 8192;
    int c0 = (idx & 63) * 64, d0 = (idx >> 6) * 64;
    const float* src; int hbase;
    if (c0 < 2048) { src = qw + (size_t)(c0 >> 8) * 524288; hbase = c0 & 255; }
    else if (c0 < 3072) { int cc = c0 - 2048; src = kw + (size_t)(cc >> 8) * 524288; hbase = cc & 255; }
    else { int cc = c0 - 3072; src = vw + (size_t)(cc >> 8) * 524288; hbase = cc & 255; }
#pragma unroll
    for (int p = 0; p < 4; ++p) {
      float4 v = *(const float4*)&src[(size_t)(d0 + ty + 16 * p) * 256 + hbase + tx * 4];
      tile[ty + 16 * p][tx * 4 + 0] = v.x; tile[ty + 16 * p][tx * 4 + 1] = v.y;
      tile[ty + 16 * p][tx * 4 + 2] = v.z; tile[ty + 16 * p][tx * 4 + 3] = v.w;
    }
    __syncthreads();
#pragma unroll
    for (int p = 0; p < 4; ++p) {
      int hh = ty + 16 * p;
      ushort4 o;
      o.x = f2bf(tile[tx * 4 + 0][hh]); o.y = f2bf(tile[tx * 4 + 1][hh]);
      o.z = f2bf(tile[tx * 4 + 2][hh]); o.w = f2bf(tile[tx * 4 + 3][hh]);
      *(ushort4*)&wqkvt[(size_t)(c0 + hh) * 2048 + d0 + tx * 4] = o;
    }
  } else {
    int idx = blk - 10240;
    int j0 = (idx & 31) * 64, d0 = (idx >> 5) * 64;
#pragma unroll
    for (int p = 0; p < 4; ++p) {
      float4 v = *(const float4*)&ow[(size_t)(j0 + ty + 16 * p) * 2048 + d0 + tx * 4];
      tile[ty + 16 * p][tx * 4 + 0] = v.x; tile[ty + 16 * p][tx * 4 + 1] = v.y;
      tile[ty + 16 * p][tx * 4 + 2] = v.z; tile[ty + 16 * p][tx * 4 + 3] = v.w;
    }
    __syncthreads();
#pragma unroll
    for (int p = 0; p < 4; ++p) {
      int hh = ty + 16 * p;
      ushort4 o;
      o.x = f2bf(tile[tx * 4 + 0][hh]); o.y = f2bf(tile[tx * 4 + 1][hh]);
      o.z = f2bf(tile[tx * 4 + 2][hh]); o.w = f2bf(tile[tx * 4 + 3][hh]);
      *(ushort4*)&wot[(size_t)(d0 + hh) * 2048 + j0 + tx * 4] = o;
    }
  }
}

// ---------------------------------------------------------------------------
// 256x256-tile 8-phase bf16 MFMA GEMM core (gemm_qkv, grid 256).
// ---------------------------------------------------------------------------
__device__ __forceinline__ void gemm256_core(
    const unsigned short* __restrict__ Ab, const unsigned short* __restrict__ Bb,
    unsigned short* lds, f32x4 acc[8][4], int aoff, int boff) {
  const int tid = threadIdx.x;

  const int l0 = tid, l1 = tid + 512;
  const int r0 = l0 >> 2, o0 = l0 & 3;
  const int r1 = l1 >> 2, o1 = l1 & 3;
  const int sA0 = r0 * 2048 + ((o0 ^ ((r0 >> 2) & 3)) << 3);
  const int sA1 = r1 * 2048 + ((o1 ^ ((r1 >> 2) & 3)) << 3);

#define STAGE(srcbase, kofs, dstbase)                  \
  do {                                                 \
    GLD16((srcbase) + sA0 + (kofs), (dstbase) + l0 * 8); \
    GLD16((srcbase) + sA1 + (kofs), (dstbase) + l1 * 8); \
  } while (0)

  STAGE(Ab, 0,  lds + 0);
  STAGE(Bb, 0,  lds + 16384);
  STAGE(Ab, 32, lds + 8192);
  STAGE(Bb, 32, lds + 24576);
  STAGE(Ab, 64, lds + 32768);
  STAGE(Bb, 64, lds + 49152);
  asm volatile("s_waitcnt vmcnt(8)" ::: "memory");
  __builtin_amdgcn_s_barrier();

  for (int t = 0; t < 32; ++t) {
    const int p = t & 1;
    unsigned short* base = lds + p * 32768;
    unsigned short* xbase = lds + (p ^ 1) * 32768;
    const int t1 = (t < 31) ? t + 1 : 31;
    const int t2 = (t < 30) ? t + 2 : 31;

    bf16x8 a[4], b[4];
    // -------- PH1 --------
#pragma unroll
    for (int i = 0; i < 4; ++i) a[i] = *(const bf16x8*)(base + aoff + i * 512);
#pragma unroll
    for (int j = 0; j < 4; ++j) b[j] = *(const bf16x8*)(base + 16384 + boff + j * 512);
    STAGE(Ab, t1 * 64 + 32, xbase + 8192);
    __builtin_amdgcn_s_barrier();
    asm volatile("s_waitcnt lgkmcnt(0)" ::: "memory");
    __builtin_amdgcn_sched_barrier(0);
    __builtin_amdgcn_s_setprio(1);
#pragma unroll
    for (int i = 0; i < 4; ++i)
#pragma unroll
      for (int j = 0; j < 4; ++j)
        acc[i][j] = __builtin_amdgcn_mfma_f32_16x16x32_bf16(a[i], b[j], acc[i][j], 0, 0, 0);
    __builtin_amdgcn_s_setprio(0);
    __builtin_amdgcn_s_barrier();

    // -------- PH2 --------
#pragma unroll
    for (int i = 0; i < 4; ++i) a[i] = *(const bf16x8*)(base + aoff + (i + 4) * 512);
    STAGE(Bb, t1 * 64 + 32, xbase + 24576);
    __builtin_amdgcn_s_barrier();
    asm volatile("s_waitcnt lgkmcnt(0)" ::: "memory");
    __builtin_amdgcn_sched_barrier(0);
    __builtin_amdgcn_s_setprio(1);
#pragma unroll
    for (int i = 0; i < 4; ++i)
#pragma unroll
      for (int j = 0; j < 4; ++j)
        acc[i + 4][j] = __builtin_amdgcn_mfma_f32_16x16x32_bf16(a[i], b[j], acc[i + 4][j], 0, 0, 0);
    __builtin_amdgcn_s_setprio(0);
    asm volatile("s_waitcnt vmcnt(8)" ::: "memory");
    __builtin_amdgcn_s_barrier();

    // -------- PH3 --------
#pragma unroll
    for (int i = 0; i < 4; ++i) a[i] = *(const bf16x8*)(base + 8192 + aoff + i * 512);
#pragma unroll
    for (int j = 0; j < 4; ++j) b[j] = *(const bf16x8*)(base + 24576 + boff + j * 512);
    STAGE(Ab, t2 * 64, base + 0);
    __builtin_amdgcn_s_barrier();
    asm volatile("s_waitcnt lgkmcnt(0)" ::: "memory");
    __builtin_amdgcn_sched_barrier(0);
    __builtin_amdgcn_s_setprio(1);
#pragma unroll
    for (int i = 0; i < 4; ++i)
#pragma unroll
      for (int j = 0; j < 4; ++j)
        acc[i][j] = __builtin_amdgcn_mfma_f32_16x16x32_bf16(a[i], b[j], acc[i][j], 0, 0, 0);
    __builtin_amdgcn_s_setprio(0);
    __builtin_amdgcn_s_barrier();

    // -------- PH4 --------
#pragma unroll
    for (int i = 0; i < 4; ++i) a[i] = *(const bf16x8*)(base + 8192 + aoff + (i + 4) * 512);
    STAGE(Bb, t2 * 64, base + 16384);
    __builtin_amdgcn_s_barrier();
    asm volatile("s_waitcnt lgkmcnt(0)" ::: "memory");
    __builtin_amdgcn_sched_barrier(0);
    __builtin_amdgcn_s_setprio(1);
#pragma unroll
    for (int i = 0; i < 4; ++i)
#pragma unroll
      for (int j = 0; j < 4; ++j)
        acc[i + 4][j] = __builtin_amdgcn_mfma_f32_16x16x32_bf16(a[i], b[j], acc[i + 4][j], 0, 0, 0);
    __builtin_amdgcn_s_setprio(0);
    asm volatile("s_waitcnt vmcnt(8)" ::: "memory");
    __builtin_amdgcn_s_barrier();
  }
#undef STAGE
}

// QKV projection: xb(4096x2048) @ wqkvt^T(4096x2048) -> q/k/v bf16
__global__ __launch_bounds__(512) void gemm_qkv_256(
    const unsigned short* __restrict__ xb, const unsigned short* __restrict__ wt,
    unsigned short* __restrict__ qo, unsigned short* __restrict__ ko,
    unsigned short* __restrict__ vo) {
  __shared__ unsigned short lds[65536];  // 128 KB
  const int tid = threadIdx.x;
  const int wave = tid >> 6, lane = tid & 63;
  const int wr = wave >> 2, wc = wave & 3;
  const int fm = lane & 15, fk = lane >> 4;

  const int bid = blockIdx.x;
  const int swz = (bid & 7) * 32 + (bid >> 3);  // nwg=256, bijective
  const int m0 = (swz >> 4) * 256, n0 = (swz & 15) * 256;

  const int soff = fm * 32 + ((fk ^ ((fm >> 2) & 3)) << 3);
  const int aoff = wr * 4096 + soff;
  const int boff = wc * 2048 + soff;

  f32x4 acc[8][4];
#pragma unroll
  for (int i = 0; i < 8; ++i)
#pragma unroll
    for (int j = 0; j < 4; ++j) acc[i][j] = {0.f, 0.f, 0.f, 0.f};

  gemm256_core(xb + (size_t)m0 * 2048, wt + (size_t)n0 * 2048, lds, acc, aoff, boff);

  unsigned short* obase; int ldo, cb;
  if (n0 < 2048) { obase = qo; ldo = 2048; cb = n0; }
  else if (n0 < 3072) { obase = ko; ldo = 1024; cb = n0 - 2048; }
  else { obase = vo; ldo = 1024; cb = n0 - 3072; }
  const int rbase = m0 + wr * 128 + (lane >> 4) * 4;
  const int cbase = cb + wc * 64 + fm;
#pragma unroll
  for (int i = 0; i < 8; ++i)
#pragma unroll
    for (int j = 0; j < 4; ++j)
#pragma unroll
      for (int r = 0; r < 4; ++r)
        obase[(size_t)(rbase + i * 16 + r) * ldo + cbase + j * 16] = f2bf(acc[i][j][r]);
}

// ---------------------------------------------------------------------------
// Output projection: abuf(4096x2048 bf16) @ wot^T -> out fp32.
// 128x256 tile -> grid 32x8 = 256 blocks = 1/CU (full chip; the r6 256x256
// version had only 128 blocks = half the CUs idle). Same 8-phase skeleton:
// 8 waves as 2Mx4N, per-wave 64x64 (acc[4][4]), 8 MFMA/phase.
// LDS 96 KB: per buffer {A kh0 8K | A kh1 8K | B kh0 16K | B kh1 16K}.
// Staging: A-half = 1 GLD16/thr, B-half = 2 -> steady-state 9 outstanding,
// retire oldest 3 -> vmcnt(6) at PH2/PH4 (prologue: 9 loads, vmcnt(6)).
// ---------------------------------------------------------------------------
__global__ __launch_bounds__(512) void gemm_out_256(
    const unsigned short* __restrict__ ab, const unsigned short* __restrict__ wot,
    float* __restrict__ out) {
  __shared__ unsigned short lds[49152];  // 96 KB
  const int tid = threadIdx.x;
  const int wave = tid >> 6, lane = tid & 63;
  const int wr = wave >> 2, wc = wave & 3;
  const int fm = lane & 15, fk = lane >> 4;

  const int bid = blockIdx.x;
  const int swz = (bid & 7) * 32 + (bid >> 3);  // nwg=256, bijective
  const int m0 = (swz >> 3) * 128, n0 = (swz & 7) * 256;

  const int soff = fm * 32 + ((fk ^ ((fm >> 2) & 3)) << 3);
  const int aoff = wr * 2048 + soff;   // A region [128][32]: wave-row 64
  const int boff = wc * 2048 + soff;   // B region [256][32]: wave-col 64

  const unsigned short* Ab = ab + (size_t)m0 * 2048;
  const unsigned short* Bb = wot + (size_t)n0 * 2048;

  // A staging: 512 x 16B chunks, 1/thread; B: 1024 chunks, 2/thread.
  const int ra = tid >> 2, oa = tid & 3;
  const int sAa = ra * 2048 + ((oa ^ ((ra >> 2) & 3)) << 3);
  const int id1 = tid + 512;
  const int rb1 = id1 >> 2, ob1 = id1 & 3;
  const int sB1 = rb1 * 2048 + ((ob1 ^ ((rb1 >> 2) & 3)) << 3);

#define STAGE_A(kofs, dstbase) GLD16(Ab + sAa + (kofs), (dstbase) + tid * 8)
#define STAGE_B(kofs, dstbase)                                   \
  do {                                                           \
    GLD16(Bb + sAa + (kofs), (dstbase) + tid * 8);               \
    GLD16(Bb + sB1 + (kofs), (dstbase) + (tid + 512) * 8);       \
  } while (0)

  f32x4 acc[4][4];
#pragma unroll
  for (int i = 0; i < 4; ++i)
#pragma unroll
    for (int j = 0; j < 4; ++j) acc[i][j] = {0.f, 0.f, 0.f, 0.f};

  // prologue: A0(0) B0(0) A1(0) B1(0) A0(1) B0(1) = 9 loads
  STAGE_A(0,  lds + 0);
  STAGE_B(0,  lds + 8192);
  STAGE_A(32, lds + 4096);
  STAGE_B(32, lds + 16384);
  STAGE_A(64, lds + 24576);
  STAGE_B(64, lds + 24576 + 8192);
  asm volatile("s_waitcnt vmcnt(6)" ::: "memory");
  __builtin_amdgcn_s_barrier();

  for (int t = 0; t < 32; ++t) {
    const int p = t & 1;
    unsigned short* base = lds + p * 24576;
    unsigned short* xbase = lds + (p ^ 1) * 24576;
    const int t1 = (t < 31) ? t + 1 : 31;
    const int t2 = (t < 30) ? t + 2 : 31;

    bf16x8 a[4], b[2];
    // -------- PH1: kh0, n-frags 0..1 --------
#pragma unroll
    for (int i = 0; i < 4; ++i) a[i] = *(const bf16x8*)(base + aoff + i * 512);
#pragma unroll
    for (int j = 0; j < 2; ++j) b[j] = *(const bf16x8*)(base + 8192 + boff + j * 512);
    STAGE_A(t1 * 64 + 32, xbase + 4096);  // A1(t+1)
    __builtin_amdgcn_s_barrier();
    asm volatile("s_waitcnt lgkmcnt(0)" ::: "memory");
    __builtin_amdgcn_sched_barrier(0);
    __builtin_amdgcn_s_setprio(1);
#pragma unroll
    for (int i = 0; i < 4; ++i)
#pragma unroll
      for (int j = 0; j < 2; ++j)
        acc[i][j] = __builtin_amdgcn_mfma_f32_16x16x32_bf16(a[i], b[j], acc[i][j], 0, 0, 0);
    __builtin_amdgcn_s_setprio(0);
    __builtin_amdgcn_s_barrier();

    // -------- PH2: kh0, n-frags 2..3 (reuse a) --------
#pragma unroll
    for (int j = 0; j < 2; ++j) b[j] = *(const bf16x8*)(base + 8192 + boff + (j + 2) * 512);
    STAGE_B(t1 * 64 + 32, xbase + 16384);  // B1(t+1)
    __builtin_amdgcn_s_barrier();
    asm volatile("s_waitcnt lgkmcnt(0)" ::: "memory");
    __builtin_amdgcn_sched_barrier(0);
    __builtin_amdgcn_s_setprio(1);
#pragma unroll
    for (int i = 0; i < 4; ++i)
#pragma unroll
      for (int j = 0; j < 2; ++j)
        acc[i][j + 2] = __builtin_amdgcn_mfma_f32_16x16x32_bf16(a[i], b[j], acc[i][j + 2], 0, 0, 0);
    __builtin_amdgcn_s_setprio(0);
    asm volatile("s_waitcnt vmcnt(6)" ::: "memory");  // A1(t),B1(t) landed
    __builtin_amdgcn_s_barrier();

    // -------- PH3: kh1, n-frags 0..1 --------
#pragma unroll
    for (int i = 0; i < 4; ++i) a[i] = *(const bf16x8*)(base + 4096 + aoff + i * 512);
#pragma unroll
    for (int j = 0; j < 2; ++j) b[j] = *(const bf16x8*)(base + 16384 + boff + j * 512);
    STAGE_A(t2 * 64, base + 0);  // A0(t+2)
    __builtin_amdgcn_s_barrier();
    asm volatile("s_waitcnt lgkmcnt(0)" ::: "memory");
    __builtin_amdgcn_sched_barrier(0);
    __builtin_amdgcn_s_setprio(1);
#pragma unroll
    for (int i = 0; i < 4; ++i)
#pragma unroll
      for (int j = 0; j < 2; ++j)
        acc[i][j] = __builtin_amdgcn_mfma_f32_16x16x32_bf16(a[i], b[j], acc[i][j], 0, 0, 0);
    __builtin_amdgcn_s_setprio(0);
    __builtin_amdgcn_s_barrier();

    // -------- PH4: kh1, n-frags 2..3 (reuse a) --------
#pragma unroll
    for (int j = 0; j < 2; ++j) b[j] = *(const bf16x8*)(base + 16384 + boff + (j + 2) * 512);
    STAGE_B(t2 * 64, base + 8192);  // B0(t+2)
    __builtin_amdgcn_s_barrier();
    asm volatile("s_waitcnt lgkmcnt(0)" ::: "memory");
    __builtin_amdgcn_sched_barrier(0);
    __builtin_amdgcn_s_setprio(1);
#pragma unroll
    for (int i = 0; i < 4; ++i)
#pragma unroll
      for (int j = 0; j < 2; ++j)
        acc[i][j + 2] = __builtin_amdgcn_mfma_f32_16x16x32_bf16(a[i], b[j], acc[i][j + 2], 0, 0, 0);
    __builtin_amdgcn_s_setprio(0);
    asm volatile("s_waitcnt vmcnt(6)" ::: "memory");  // A0(t+1),B0(t+1) landed
    __builtin_amdgcn_s_barrier();
  }
#undef STAGE_A
#undef STAGE_B

  const int rbase = m0 + wr * 64 + (lane >> 4) * 4;
  const int cbase = n0 + wc * 64 + fm;
#pragma unroll
  for (int i = 0; i < 4; ++i)
#pragma unroll
    for (int j = 0; j < 4; ++j)
#pragma unroll
      for (int r = 0; r < 4; ++r)
        out[(size_t)(rbase + i * 16 + r) * 2048 + cbase + j * 16] = acc[i][j][r];
}

// ---------------------------------------------------------------------------
// postproc: fused RMSNorm+RoPE (q in-place, k -> swizzled panels) + V panelize.
// ---------------------------------------------------------------------------
__global__ __launch_bounds__(256) void postproc(
    unsigned short* __restrict__ qb, const unsigned short* __restrict__ kb,
    unsigned short* __restrict__ kpan,
    const unsigned short* __restrict__ vbf, unsigned short* __restrict__ vpan,
    const int* __restrict__ positions,
    const float* __restrict__ qns, const float* __restrict__ kns) {
  const int blk = blockIdx.x;
  const int tid = threadIdx.x;
  if (blk < 12288) {
    int row = blk * 4 + (tid >> 6);
    int lane = tid & 63;
    const unsigned short* src; const float* ns; float extra; int bt;
    bool isq = row < 32768;
    if (isq) {
      src = qb + (size_t)row * 256; ns = qns; extra = 0.0625f; bt = row >> 3;
    } else {
      int r = row - 32768;
      src = kb + (size_t)r * 256; ns = kns; extra = 1.0f; bt = r >> 2;
    }
    int pos = positions[bt];

    ushort4 u = *(const ushort4*)&src[lane << 2];
    float xv[4] = {bf2f(u.x), bf2f(u.y), bf2f(u.z), bf2f(u.w)};
    float ss = xv[0]*xv[0] + xv[1]*xv[1] + xv[2]*xv[2] + xv[3]*xv[3];
#pragma unroll
    for (int off = 1; off < 64; off <<= 1) ss += __shfl_xor(ss, off, 64);
    float rinv = rsqrtf(ss * (1.0f / 256.0f) + 1e-6f);

    float4 sc4 = *(const float4*)&ns[lane << 2];
    xv[0] *= rinv * (1.0f + sc4.x);
    xv[1] *= rinv * (1.0f + sc4.y);
    xv[2] *= rinv * (1.0f + sc4.z);
    xv[3] *= rinv * (1.0f + sc4.w);

    float ov[4];
#pragma unroll
    for (int c = 0; c < 4; ++c) ov[c] = __shfl_xor(xv[c], 32, 64);

    int hr = (lane & 31) << 2;
    float sgn = (lane < 32) ? -1.0f : 1.0f;
    ushort4 w4;
    unsigned short res[4];
#pragma unroll
    for (int c = 0; c < 4; ++c) {
      float invts = exp2f(-(float)(hr + c) * 0.10381025296523007f);
      float angle = (float)pos * invts;
      float sn, cs;
      __sincosf(angle, &sn, &cs);
      res[c] = f2bf((xv[c] * cs + sgn * ov[c] * sn) * extra);
    }
    w4.x = res[0]; w4.y = res[1]; w4.z = res[2]; w4.w = res[3];
    if (isq) {
      *(ushort4*)&qb[(size_t)row * 256 + (lane << 2)] = w4;
    } else {
      int r = row - 32768;
      int kvh = r & 3;
      int b_ = bt >> 11, t = bt & 2047;
      unsigned short* pan = kpan + (((size_t)(b_ * 4 + kvh) * 64 + (t >> 5)) * 8192);
      int s = t & 31;
      int c = lane >> 1;
      size_t el = (size_t)s * 256 + (size_t)((c ^ s) & 31) * 8 + (lane & 1) * 4;
      *(ushort4*)&pan[el] = w4;
    }
    return;
  }
  // ---- V panelize ----
  __shared__ unsigned short tile[64][68];
  int idx = blk - 12288;
  int h0 = (idx & 3) * 64;
  int t0 = ((idx >> 2) & 31) * 64;
  int z = idx >> 7;  // b*4 + kvh
  int tx = tid & 15, ty = tid >> 4;
  const unsigned short* src = vbf + ((size_t)(z >> 2) * 8192 + (z & 3)) * 256;
#pragma unroll
  for (int p = 0; p < 4; ++p) {
    ushort4 v = *(const ushort4*)&src[(size_t)(t0 + ty + 16 * p) * 1024 + h0 + tx * 4];
    tile[ty + 16 * p][tx * 4 + 0] = v.x; tile[ty + 16 * p][tx * 4 + 1] = v.y;
    tile[ty + 16 * p][tx * 4 + 2] = v.z; tile[ty + 16 * p][tx * 4 + 3] = v.w;
  }
  __syncthreads();
#pragma unroll
  for (int p = 0; p < 4; ++p) {
    int hh = ty + 16 * p;
    int h = h0 + hh;
    int t = t0 + tx * 4;
    int pp = t >> 5, s = t & 31;
    ushort4 o;
    o.x = tile[tx * 4 + 0][hh]; o.y = tile[tx * 4 + 1][hh];
    o.z = tile[tx * 4 + 2][hh]; o.w = tile[tx * 4 + 3][hh];
    size_t el = ((size_t)z * 64 + pp) * 8192 + (size_t)h * 32 +
                (size_t)(((s >> 3) ^ h ^ (h >> 2)) & 3) * 8 + (s & 7);
    *(ushort4*)&vpan[el] = o;
  }
}

// ---------------------------------------------------------------------------
// MFMA sliding-window attention, 32x32x16 bf16, static-max softmax.
// Round-6 structure (84.3 us) + LPT block order: low blockIdx (dispatched
// first) -> large t0 (33-tile windows) so long blocks start first and short
// ones backfill the tail.
// ---------------------------------------------------------------------------
__global__ __launch_bounds__(128) void attn_mfma(
    const unsigned short* __restrict__ qb,    // [b][t][8][256]
    const unsigned short* __restrict__ kpan,  // [b*4+kvh][p][32 s][swz 512B]
    const unsigned short* __restrict__ vpan,  // [b*4+kvh][p][256 h][swz 64B]
    unsigned short* __restrict__ ob) {        // [b][t][8][256]
  __shared__ __align__(16) unsigned short Kl[8192];  // [s 32][chunk 32][8]
  __shared__ __align__(16) unsigned short Vl[8192];  // [h 256][chunk 4][8]
  __shared__ __align__(16) unsigned short Ps[3072];  // [w][half 2][m 32][24]

  const int tid = threadIdx.x;
  const int w = tid >> 6, lane = tid & 63;
  const int l5 = lane >> 5, l31 = lane & 31;
  const int pair = blockIdx.x & 7;
  const int t0 = (63 - (blockIdx.x >> 3)) * 32;  // LPT: longest first
  const int kvh = pair >> 1, b = pair & 1;
  const int n = 2 * kvh + w;
  const int tmin = t0, tmax = t0 + 31;

  // Q fragments in registers (A-operand: m=l31 row, k-octet=l5)
  bf16x8 aq[16];
  {
    const unsigned short* qrow =
        qb + (((size_t)b * 2048 + tmin + l31) * 8 + n) * 256 + l5 * 8;
#pragma unroll
    for (int kc = 0; kc < 16; ++kc) aq[kc] = *(const bf16x8*)(qrow + kc * 16);
  }

  f32x16 O[8], lsum;
#pragma unroll
  for (int i = 0; i < 8; ++i)
#pragma unroll
    for (int r = 0; r < 16; ++r) O[i][r] = 0.f;
#pragma unroll
  for (int r = 0; r < 16; ++r) lsum[r] = 0.f;

  bf16x8 ones;
#pragma unroll
  for (int i = 0; i < 8; ++i) ones[i] = (short)0x3F80;  // bf16 1.0

  const unsigned short* kpb = kpan + (size_t)(b * 4 + kvh) * 64 * 8192;
  const unsigned short* vpb = vpan + (size_t)(b * 4 + kvh) * 64 * 8192;

  int s_lo = t0 - 1024; if (s_lo < 0) s_lo = 0;
  const int s_end = t0 + 32;

  for (int s0 = s_lo; s0 < s_end; s0 += 32) {
    __syncthreads();  // both waves done reading Kl/Vl from previous step
    const unsigned short* kp = kpb + (size_t)(s0 >> 5) * 8192;
    const unsigned short* vp = vpb + (size_t)(s0 >> 5) * 8192;
#pragma unroll
    for (int j = 0; j < 8; ++j) {
      int g = j * 128 + tid;
      GLD16(kp + g * 8, Kl + g * 8);
    }
#pragma unroll
    for (int j = 0; j < 8; ++j) {
      int g = j * 128 + tid;
      GLD16(vp + g * 8, Vl + g * 8);
    }
    __syncthreads();  // staging complete

    // S = Q K^T (two parallel accumulation chains)
    f32x16 pa, pb;
#pragma unroll
    for (int r = 0; r < 16; ++r) { pa[r] = 0.f; pb[r] = 0.f; }
#pragma unroll
    for (int kc = 0; kc < 16; kc += 2) {
      bf16x8 b0 = *(const bf16x8*)&Kl[l31 * 256 + (((kc * 2 + l5) ^ l31) & 31) * 8];
      bf16x8 b1 = *(const bf16x8*)&Kl[l31 * 256 + ((((kc + 1) * 2 + l5) ^ l31) & 31) * 8];
      pa = __builtin_amdgcn_mfma_f32_32x32x16_bf16(aq[kc], b0, pa, 0, 0, 0);
      pb = __builtin_amdgcn_mfma_f32_32x32x16_bf16(aq[kc + 1], b1, pb, 0, 0, 0);
    }

    bool allvalid = (s0 + 31 <= tmin) && (s0 >= tmax - 1023);
    int scol = s0 + l31;
    // P = exp(S), mask -> 0; write to Ps as bf16 (A-layout, wave-private)
#pragma unroll
    for (int r = 0; r < 16; ++r) {
      float sv = pa[r] + pb[r];
      float p = exp2f(sv * 1.442695040888963f);
      int m = (r & 3) + 8 * (r >> 2) + 4 * l5;
      if (!allvalid) {
        int dt = (tmin + m) - scol;
        p = (dt >= 0 && dt < 1024) ? p : 0.f;
      }
      Ps[w * 1536 + (l31 >> 4) * 768 + m * 24 + (l31 & 15)] = f2bf(p);
    }

    // PV + row-sum (wave-private Ps: no barrier needed)
    bf16x8 pf0 = *(const bf16x8*)&Ps[w * 1536 + l31 * 24 + l5 * 8];
    bf16x8 pf1 = *(const bf16x8*)&Ps[w * 1536 + 768 + l31 * 24 + l5 * 8];
    lsum = __builtin_amdgcn_mfma_f32_32x32x16_bf16(pf0, ones, lsum, 0, 0, 0);
    lsum = __builtin_amdgcn_mfma_f32_32x32x16_bf16(pf1, ones, lsum, 0, 0, 0);
#pragma unroll
    for (int hb = 0; hb < 8; ++hb) {
      int row = hb * 32 + l31;
      int gh = (row ^ (row >> 2)) & 3;
      bf16x8 v0 = *(const bf16x8*)&Vl[row * 32 + ((l5 ^ gh) & 3) * 8];
      bf16x8 v1 = *(const bf16x8*)&Vl[row * 32 + (((2 + l5) ^ gh) & 3) * 8];
      O[hb] = __builtin_amdgcn_mfma_f32_32x32x16_bf16(pf0, v0, O[hb], 0, 0, 0);
      O[hb] = __builtin_amdgcn_mfma_f32_32x32x16_bf16(pf1, v1, O[hb], 0, 0, 0);
    }
  }

  // epilogue: normalize and store bf16
  unsigned short* obase = ob + (((size_t)b * 2048 + tmin) * 8 + n) * 256;
#pragma unroll
  for (int r = 0; r < 16; ++r) {
    int m = (r & 3) + 8 * (r >> 2) + 4 * l5;
    float rinv = 1.0f / lsum[r];
    size_t rowoff = (size_t)m * 2048;
#pragma unroll
    for (int hb = 0; hb < 8; ++hb)
      obase[rowoff + hb * 32 + l31] = f2bf(O[hb][r] * rinv);
  }
}

extern "C" void kernel_launch(void* const* d_in, const int* in_sizes, int n_in,
                              void* d_out, int out_size, void* d_ws, size_t ws_size,
                              hipStream_t stream) {
  const float* x   = (const float*)d_in[0];
  const int* pos   = (const int*)d_in[1];
  const float* q_w = (const float*)d_in[2];
  const float* k_w = (const float*)d_in[3];
  const float* v_w = (const float*)d_in[4];
  const float* o_w = (const float*)d_in[5];
  const float* qns = (const float*)d_in[6];
  const float* kns = (const float*)d_in[7];
  float* out = (float*)d_out;

  unsigned short* W = (unsigned short*)d_ws;
  unsigned short* qb0   = W;               //  8,388,608 us  q bf16
  unsigned short* kb0   = W + 8388608;     //  4,194,304 us  k bf16 (row-major)
  unsigned short* vbf   = W + 12582912;    //  4,194,304 us  v bf16 (row-major)
  unsigned short* vpan  = W + 16777216;    //  4,194,304 us  v panels (swizzled)
  unsigned short* kpan  = W + 20971520;    //  4,194,304 us  k panels (swizzled)
  unsigned short* xb    = W + 25165824;    //  8,388,608 us  x bf16
  unsigned short* wqkvt = W + 33554432;    //  8,388,608 us  qkv weights^T
  unsigned short* abuf  = wqkvt;           //  reuse after gemm_qkv
  unsigned short* wot   = W + 41943040;    //  4,194,304 us  o weights^T
  // total 46,137,344 us = 92.3 MB

  prep<<<dim3(11264), 256, 0, stream>>>(x, q_w, k_w, v_w, o_w, xb, wqkvt, wot);
  gemm_qkv_256<<<dim3(256), 512, 0, stream>>>(xb, wqkvt, qb0, kb0, vbf);
  postproc<<<dim3(13312), 256, 0, stream>>>(qb0, kb0, kpan, vbf, vpan, pos, qns, kns);
  attn_mfma<<<dim3(512), 128, 0, stream>>>(qb0, kpan, vpan, abuf);
  gemm_out_256<<<dim3(256), 512, 0, stream>>>(abuf, wot, out);
}